// Round 3
// baseline (2599.423 us; speedup 1.0000x reference)
//
#include <hip/hip_runtime.h>
#include <hip/hip_bf16.h>

#define SS  128
#define DD  512
#define NHH 8
#define DHH 64
#define KC  32

typedef float f4 __attribute__((ext_vector_type(4)));

// One block per (b, h). 256 threads = 4 waves.
// Everything upstream of the floor() is computed in f64 (floor-boundary flips
// against the f64 numpy reference were the Round-2 failure: qk/8 ~ N(0,1),
// f32 qk error ~1e-5 -> ~20 boundary flips over 1M scores -> absmax 6.5e-2).
// Phase 1: q = x_non[b] @ Wq_h^T + bq_h          (f64 accumulate)
// Phase 2: K (f64 acc regs), V (f32) = x_seq[b] @ {Wk,Wv}_h^T  (LDS-tiled)
// Phase 3: qk in f64 (shfl-reduce), floor(/8) in f64, mask
// Phase 4: softmax f32 + z = attn @ V (f32)
__global__ __launch_bounds__(256) void mha_f64_kernel(
    const float* __restrict__ x_non,
    const float* __restrict__ x_seq,
    const int*   __restrict__ mask,
    const float* __restrict__ Wq, const float* __restrict__ bq,
    const float* __restrict__ Wk, const float* __restrict__ bk,
    const float* __restrict__ Wv, const float* __restrict__ bv,
    float*       __restrict__ out)
{
    const int tid = threadIdx.x;
    const int b   = blockIdx.x >> 3;
    const int h   = blockIdx.x & 7;

    __shared__ __attribute__((aligned(16))) union {
        struct { float Xs[128][36]; float Wks[64][36]; float Wvs[64][36]; } p1; // 36864 B
        struct { float Vs[128][64]; } p2;                                       // 32768 B
    } u;
    __shared__ double qsd[64];
    __shared__ float  ps[128];
    __shared__ float  zpart[4][64];

    // ---- phase 1: q (f64 accumulate). n = tid>>2, 4 lanes split K=512 ----
    {
        const int n  = tid >> 2;
        const int kq = (tid & 3) * 128;
        const float* xr = x_non + (size_t)b * DD + kq;
        const float* wr = Wq + (size_t)(h * DHH + n) * DD + kq;
        double acc = 0.0;
        #pragma unroll
        for (int j = 0; j < 128; j += 4) {
            f4 xv = *(const f4*)(xr + j);
            f4 wv = *(const f4*)(wr + j);
            #pragma unroll
            for (int e = 0; e < 4; ++e) acc += (double)xv[e] * (double)wv[e];
        }
        acc += __shfl_xor(acc, 1);
        acc += __shfl_xor(acc, 2);
        if ((tid & 3) == 0) qsd[n] = acc + (double)bq[h * DHH + n];
    }

    // ---- phase 2: thread (tr,tc) owns rows tr+16i, cols tc+16j ----
    const int tr = tid >> 4;   // 0..15
    const int tc = tid & 15;   // 0..15
    double accK[8][4];
    float  accV[8][4];
    #pragma unroll
    for (int i = 0; i < 8; ++i)
        #pragma unroll
        for (int j = 0; j < 4; ++j) { accK[i][j] = 0.0; accV[i][j] = 0.f; }

    for (int kc = 0; kc < DD / KC; ++kc) {
        __syncthreads();
        #pragma unroll
        for (int p = 0; p < 4; ++p) {
            int g = tid + 256 * p;
            int r = g >> 3, c4 = (g & 7) << 2;
            *(f4*)&u.p1.Xs[r][c4] =
                *(const f4*)(x_seq + ((size_t)(b * SS + r)) * DD + kc * KC + c4);
        }
        #pragma unroll
        for (int p = 0; p < 2; ++p) {
            int g = tid + 256 * p;
            int r = g >> 3, c4 = (g & 7) << 2;
            size_t off = (size_t)(h * DHH + r) * DD + kc * KC + c4;
            *(f4*)&u.p1.Wks[r][c4] = *(const f4*)(Wk + off);
            *(f4*)&u.p1.Wvs[r][c4] = *(const f4*)(Wv + off);
        }
        __syncthreads();
        for (int kk = 0; kk < KC; kk += 4) {
            f4 xv[8], wkv[4], wvv[4];
            #pragma unroll
            for (int i = 0; i < 8; ++i) xv[i] = *(const f4*)&u.p1.Xs[tr + 16 * i][kk];
            #pragma unroll
            for (int j = 0; j < 4; ++j) {
                wkv[j] = *(const f4*)&u.p1.Wks[tc + 16 * j][kk];
                wvv[j] = *(const f4*)&u.p1.Wvs[tc + 16 * j][kk];
            }
            #pragma unroll
            for (int e = 0; e < 4; ++e) {
                double xd[8], wkd[4];
                #pragma unroll
                for (int i = 0; i < 8; ++i) xd[i] = (double)xv[i][e];
                #pragma unroll
                for (int j = 0; j < 4; ++j) wkd[j] = (double)wkv[j][e];
                #pragma unroll
                for (int i = 0; i < 8; ++i)
                    #pragma unroll
                    for (int j = 0; j < 4; ++j) {
                        accK[i][j] = fma(xd[i], wkd[j], accK[i][j]);
                        accV[i][j] += xv[i][e] * wvv[j][e];
                    }
            }
        }
    }
    __syncthreads();   // last read of p1 done; p2 aliases it

    // ---- spill V (+bias) to LDS ----
    {
        float bvv[4];
        #pragma unroll
        for (int j = 0; j < 4; ++j) bvv[j] = bv[h * DHH + tc + 16 * j];
        #pragma unroll
        for (int i = 0; i < 8; ++i)
            #pragma unroll
            for (int j = 0; j < 4; ++j)
                u.p2.Vs[tr + 16 * i][tc + 16 * j] = accV[i][j] + bvv[j];
    }

    // ---- phase 3: qk in f64, floor, mask ----
    {
        double bkd[4], qd[4];
        #pragma unroll
        for (int j = 0; j < 4; ++j) {
            bkd[j] = (double)bk[h * DHH + tc + 16 * j];
            qd[j]  = qsd[tc + 16 * j];
        }
        #pragma unroll
        for (int i = 0; i < 8; ++i) {
            double p = 0.0;
            #pragma unroll
            for (int j = 0; j < 4; ++j) p = fma(qd[j], accK[i][j] + bkd[j], p);
            p += __shfl_xor(p, 1);
            p += __shfl_xor(p, 2);
            p += __shfl_xor(p, 4);
            p += __shfl_xor(p, 8);
            if (tc == 0) {
                const int s = tr + 16 * i;
                double sc = floor(p * 0.125);   // /8 exact
                if (mask[((size_t)b * NHH + h) * SS + s] == 0) sc = -1e9;
                ps[s] = (float)sc;
            }
        }
    }
    __syncthreads();

    // ---- softmax (f32, redundant in all threads) ----
    float mx = -1e30f;
    for (int s = 0; s < 128; ++s) mx = fmaxf(mx, ps[s]);
    __syncthreads();
    if (tid < 128) ps[tid] = expf(ps[tid] - mx);
    __syncthreads();
    float lsum = 0.f;
    for (int s = 0; s < 128; ++s) lsum += ps[s];

    // ---- phase 4: z = attn @ V ----
    const int w = tid >> 6, l = tid & 63;
    {
        float z = 0.f;
        for (int s = 32 * w; s < 32 * w + 32; ++s)
            z += ps[s] * u.p2.Vs[s][l];
        zpart[w][l] = z;
    }
    __syncthreads();
    if (tid < 64) {
        float zz = (zpart[0][tid] + zpart[1][tid] + zpart[2][tid] + zpart[3][tid]) / lsum;
        out[(size_t)b * DD + h * DHH + tid] = zz;
    }
}

extern "C" void kernel_launch(void* const* d_in, const int* in_sizes, int n_in,
                              void* d_out, int out_size, void* d_ws, size_t ws_size,
                              hipStream_t stream) {
    const float* x_non = (const float*)d_in[0];
    const float* x_seq = (const float*)d_in[1];
    const int*   mask  = (const int*)d_in[2];
    const float* Wq    = (const float*)d_in[3];
    const float* bq    = (const float*)d_in[4];
    const float* Wk    = (const float*)d_in[5];
    const float* bk    = (const float*)d_in[6];
    const float* Wv    = (const float*)d_in[7];
    const float* bv    = (const float*)d_in[8];
    float*       out   = (float*)d_out;

    dim3 grid(1024 * NHH), block(256);
    mha_f64_kernel<<<grid, block, 0, stream>>>(x_non, x_seq, mask,
                                               Wq, bq, Wk, bk, Wv, bv, out);
}

// Round 4
// 1199.195 us; speedup vs baseline: 2.1676x; 2.1676x over previous
//
#include <hip/hip_runtime.h>

#define SS  128
#define DD  512
#define NHH 8
#define DHH 64

typedef float  f4 __attribute__((ext_vector_type(4)));
typedef double d2 __attribute__((ext_vector_type(2)));

// One block per batch b (1024 blocks, 256 threads). All 8 heads per block so
// every X=x_seq[b] element is read once per pass (2 passes: scores, u).
//
// Reassociated algebra (f64 upstream of floor -- floors must match f64 numpy ref):
//   q   = x_non[b] @ Wq^T + bq                    (512 outs, f64)
//   t_h = Wk_h^T q_h   (per head, 512-vec, f64);  qbk_h = q_h . bk_h
//   qk[s,h] = X[s] . t_h + qbk_h   -> floor(/8), mask  (f64)
//   attn = softmax (f32), unnormalized exp + row sums
//   u_h = attn_h @ X   (f32);  z = (u_h . Wv[o,:])/lsum_h + bv[o]  (f32)
// This removes the K and V GEMMs entirely: 8.6M MACs/block -> 2.3M.
__global__ __launch_bounds__(256) void mha_reassoc_kernel(
    const float* __restrict__ x_non,
    const float* __restrict__ x_seq,
    const int*   __restrict__ mask,
    const float* __restrict__ Wq, const float* __restrict__ bq,
    const float* __restrict__ Wk, const float* __restrict__ bk,
    const float* __restrict__ Wv, const float* __restrict__ bv,
    float*       __restrict__ out)
{
    const int tid = threadIdx.x;
    const int b   = blockIdx.x;

    // Overlay: T (P2/P3) -> P partials (P3 end) -> u (P5). Temporally disjoint.
    __shared__ __attribute__((aligned(16))) union {
        struct { float  xnb[512]; }        p0;   // 2 KB   (P0/P1 only)
        struct { double T[512][9]; }       pt;   // 36.9 KB (pad 9: P2-write 2-way)
        struct { double P[4][128][8]; }    pr;   // 32 KB  (k-quarter partials)
        struct { float  u[8][512]; }       pu;   // 16 KB
    } sh;
    __shared__ double qd[512];
    __shared__ double qbks[8];
    __shared__ __attribute__((aligned(16))) float attn[8][128];
    __shared__ float lsums[8];

    const float* Xb = x_seq + (size_t)b * (SS * DD);

    // ---- P0: stage x_non[b] ----
    sh.p0.xnb[tid]       = x_non[(size_t)b * DD + tid];
    sh.p0.xnb[tid + 256] = x_non[(size_t)b * DD + tid + 256];
    __syncthreads();

    // ---- P1: q = x_non @ Wq^T + bq (f64). Outputs o=tid, o2=tid+256 ----
    {
        const float* w1 = Wq + (size_t)tid * DD;
        const float* w2 = Wq + ((size_t)tid + 256) * DD;
        double a1 = 0.0, a2 = 0.0;
        for (int k = 0; k < DD; k += 4) {
            f4 xv  = *(const f4*)&sh.p0.xnb[k];
            f4 wv1 = *(const f4*)(w1 + k);
            f4 wv2 = *(const f4*)(w2 + k);
            #pragma unroll
            for (int e = 0; e < 4; ++e) {
                double xd = (double)xv[e];
                a1 = fma(xd, (double)wv1[e], a1);
                a2 = fma(xd, (double)wv2[e], a2);
            }
        }
        double q1 = a1 + (double)bq[tid];
        double q2 = a2 + (double)bq[tid + 256];
        __syncthreads();              // xnb last read above; T aliases it next
        qd[tid]       = q1;
        qd[tid + 256] = q2;
    }
    __syncthreads();

    // ---- P2: T[k][h] = sum_d Wk[h*64+d][k] * q[h*64+d]  (k = tid, tid+256) ----
    for (int h = 0; h < NHH; ++h) {
        const float* wb = Wk + ((size_t)h * DHH) * DD;
        double a1 = 0.0, a2 = 0.0;
        for (int d = 0; d < DHH; d += 2) {
            d2 qv = *(const d2*)&qd[h * DHH + d];
            a1 = fma((double)wb[(size_t)d * DD + tid],             qv[0], a1);
            a2 = fma((double)wb[(size_t)d * DD + tid + 256],       qv[0], a2);
            a1 = fma((double)wb[(size_t)(d + 1) * DD + tid],       qv[1], a1);
            a2 = fma((double)wb[(size_t)(d + 1) * DD + tid + 256], qv[1], a2);
        }
        sh.pt.T[tid][h]       = a1;
        sh.pt.T[tid + 256][h] = a2;
    }
    if (tid < NHH) {
        double s = 0.0;
        for (int d = 0; d < DHH; ++d)
            s = fma(qd[tid * DHH + d], (double)bk[tid * DHH + d], s);
        qbks[tid] = s;
    }
    __syncthreads();

    // ---- P3: qk partials. Wave = k-quarter (uniform k -> T broadcast reads).
    //      Lane l owns rows s=l and s=l+64, k in [128q, 128q+128). ----
    const int q = tid >> 6;
    const int l = tid & 63;
    double acc0[NHH], acc1[NHH];
    #pragma unroll
    for (int h = 0; h < NHH; ++h) { acc0[h] = 0.0; acc1[h] = 0.0; }
    {
        const int k0 = q * 128;
        const float* xa = Xb + (size_t)l * DD + k0;
        const float* xc = Xb + ((size_t)l + 64) * DD + k0;
        for (int j = 0; j < 128; j += 4) {
            f4 xva = *(const f4*)(xa + j);
            f4 xvc = *(const f4*)(xc + j);
            #pragma unroll
            for (int e = 0; e < 4; ++e) {
                double xda = (double)xva[e];
                double xdc = (double)xvc[e];
                const double* Tr = sh.pt.T[k0 + j + e];
                #pragma unroll
                for (int h = 0; h < NHH; ++h) {
                    double tv = Tr[h];
                    acc0[h] = fma(xda, tv, acc0[h]);
                    acc1[h] = fma(xdc, tv, acc1[h]);
                }
            }
        }
    }
    __syncthreads();                  // all waves done reading T
    #pragma unroll
    for (int h = 0; h < NHH; ++h) {
        sh.pr.P[q][l][h]      = acc0[h];
        sh.pr.P[q][l + 64][h] = acc1[h];
    }
    __syncthreads();

    // ---- reduce quarters -> logits: floor((qk+qbk)/8), mask ----
    #pragma unroll
    for (int p = 0; p < 4; ++p) {
        int slot = tid + 256 * p;            // 1024 = 128 s x 8 h
        int s2 = slot >> 3, h = slot & 7;
        double tot = sh.pr.P[0][s2][h] + sh.pr.P[1][s2][h]
                   + sh.pr.P[2][s2][h] + sh.pr.P[3][s2][h];
        double sc = floor((tot + qbks[h]) * 0.125);
        if (mask[((size_t)b * NHH + h) * SS + s2] == 0) sc = -1e9;
        attn[h][s2] = (float)sc;
    }
    __syncthreads();

    // ---- P4: softmax per head (group of 32 lanes per h), unnormalized ----
    {
        const int h = tid >> 5;
        const int i = tid & 31;
        float v[4], mx = -3e38f;
        #pragma unroll
        for (int jj = 0; jj < 4; ++jj) { v[jj] = attn[h][i + 32 * jj]; mx = fmaxf(mx, v[jj]); }
        #pragma unroll
        for (int off = 1; off < 32; off <<= 1) mx = fmaxf(mx, __shfl_xor(mx, off, 32));
        float sum = 0.f;
        #pragma unroll
        for (int jj = 0; jj < 4; ++jj) { v[jj] = expf(v[jj] - mx); sum += v[jj]; }
        #pragma unroll
        for (int off = 1; off < 32; off <<= 1) sum += __shfl_xor(sum, off, 32);
        #pragma unroll
        for (int jj = 0; jj < 4; ++jj) attn[h][i + 32 * jj] = v[jj];
        if (i == 0) lsums[h] = sum;
    }
    __syncthreads();

    // ---- P5: u[h][k] = sum_s attn[h][s] * X[s][k]  (f32, k = tid, tid+256) ----
    {
        float a1[NHH], a2[NHH];
        #pragma unroll
        for (int h = 0; h < NHH; ++h) { a1[h] = 0.f; a2[h] = 0.f; }
        for (int s2 = 0; s2 < SS; s2 += 4) {
            f4 av[NHH];
            #pragma unroll
            for (int h = 0; h < NHH; ++h) av[h] = *(const f4*)&attn[h][s2];
            #pragma unroll
            for (int e = 0; e < 4; ++e) {
                float x1 = Xb[(size_t)(s2 + e) * DD + tid];
                float x2 = Xb[(size_t)(s2 + e) * DD + tid + 256];
                #pragma unroll
                for (int h = 0; h < NHH; ++h) {
                    a1[h] = fmaf(av[h][e], x1, a1[h]);
                    a2[h] = fmaf(av[h][e], x2, a2[h]);
                }
            }
        }
        #pragma unroll
        for (int h = 0; h < NHH; ++h) {
            sh.pu.u[h][tid]       = a1[h];
            sh.pu.u[h][tid + 256] = a2[h];
        }
    }
    __syncthreads();

    // ---- P6: z[o] = (u[h] . Wv[o,:]) / lsum_h + bv[o] ----
    {
        const int o1 = tid, o2 = tid + 256;
        const int h1 = o1 >> 6, h2 = o2 >> 6;
        const float* w1 = Wv + (size_t)o1 * DD;
        const float* w2 = Wv + (size_t)o2 * DD;
        float a1 = 0.f, a2 = 0.f;
        for (int k = 0; k < DD; k += 4) {
            f4 u1  = *(const f4*)&sh.pu.u[h1][k];
            f4 u2  = *(const f4*)&sh.pu.u[h2][k];
            f4 wv1 = *(const f4*)(w1 + k);
            f4 wv2 = *(const f4*)(w2 + k);
            #pragma unroll
            for (int e = 0; e < 4; ++e) {
                a1 = fmaf(u1[e], wv1[e], a1);
                a2 = fmaf(u2[e], wv2[e], a2);
            }
        }
        out[(size_t)b * DD + o1] = a1 / lsums[h1] + bv[o1];
        out[(size_t)b * DD + o2] = a2 / lsums[h2] + bv[o2];
    }
}

extern "C" void kernel_launch(void* const* d_in, const int* in_sizes, int n_in,
                              void* d_out, int out_size, void* d_ws, size_t ws_size,
                              hipStream_t stream) {
    const float* x_non = (const float*)d_in[0];
    const float* x_seq = (const float*)d_in[1];
    const int*   mask  = (const int*)d_in[2];
    const float* Wq    = (const float*)d_in[3];
    const float* bq    = (const float*)d_in[4];
    const float* Wk    = (const float*)d_in[5];
    const float* bk    = (const float*)d_in[6];
    const float* Wv    = (const float*)d_in[7];
    const float* bv    = (const float*)d_in[8];
    float*       out   = (float*)d_out;

    dim3 grid(1024), block(256);
    mha_reassoc_kernel<<<grid, block, 0, stream>>>(x_non, x_seq, mask,
                                                   Wq, bq, Wk, bk, Wv, bv, out);
}

// Round 5
// 529.454 us; speedup vs baseline: 4.9096x; 2.2650x over previous
//
#include <hip/hip_runtime.h>

#define SS  128
#define DD  512
#define NHH 8
#define DHH 64

typedef float  f4 __attribute__((ext_vector_type(4)));
typedef double d2 __attribute__((ext_vector_type(2)));

// ================= K1: q[b,o] = x_non[b] . Wq[o,:] + bq[o]  (f64 acc) =========
// 256 blocks: 32 b-tiles (32 rows) x 8 o-tiles (64 cols). K=512 in 8 chunks.
__global__ __launch_bounds__(256) void qproj_kernel(
    const float* __restrict__ x_non, const float* __restrict__ Wq,
    const float* __restrict__ bq, double* __restrict__ qws)
{
    const int tid = threadIdx.x;
    const int bt  = blockIdx.x & 31;
    const int ot  = blockIdx.x >> 5;
    const int r   = tid >> 4, c = tid & 15;

    __shared__ __attribute__((aligned(16))) float Xs[32][68];
    __shared__ __attribute__((aligned(16))) float Ws[64][68];

    double acc[2][4];
    #pragma unroll
    for (int i = 0; i < 2; ++i)
        #pragma unroll
        for (int j = 0; j < 4; ++j) acc[i][j] = 0.0;

    for (int kc = 0; kc < 8; ++kc) {
        __syncthreads();
        #pragma unroll
        for (int p = 0; p < 2; ++p) {               // X tile: 32 x 64
            int s = tid + 256 * p, rr = s >> 4, cc = (s & 15) * 4;
            *(f4*)&Xs[rr][cc] = *(const f4*)(x_non + (size_t)(bt * 32 + rr) * DD + kc * 64 + cc);
        }
        #pragma unroll
        for (int p = 0; p < 4; ++p) {               // Wq tile: 64 x 64
            int s = tid + 256 * p, rr = s >> 4, cc = (s & 15) * 4;
            *(f4*)&Ws[rr][cc] = *(const f4*)(Wq + (size_t)(ot * 64 + rr) * DD + kc * 64 + cc);
        }
        __syncthreads();
        #pragma unroll 4
        for (int kk = 0; kk < 64; ++kk) {
            double a0 = (double)Xs[r][kk];
            double a1 = (double)Xs[r + 16][kk];
            #pragma unroll
            for (int j = 0; j < 4; ++j) {
                double bb = (double)Ws[c + 16 * j][kk];
                acc[0][j] = fma(a0, bb, acc[0][j]);
                acc[1][j] = fma(a1, bb, acc[1][j]);
            }
        }
    }
    #pragma unroll
    for (int i = 0; i < 2; ++i)
        #pragma unroll
        for (int j = 0; j < 4; ++j) {
            int o = ot * 64 + c + 16 * j;
            qws[(size_t)(bt * 32 + r + 16 * i) * DD + o] = acc[i][j] + (double)bq[o];
        }
}

// ================= K2: per-b attention core ===================================
// t[h,k] = Wk_h^T q_h (f64, coalesced Wk); qk = X.t + q.bk -> floor/8, mask;
// softmax; u'[h,k] = (attn_h @ X)/lsum_h -> ws.
__global__ __launch_bounds__(256) void core_kernel(
    const double* __restrict__ qws, const float* __restrict__ x_seq,
    const int* __restrict__ mask, const float* __restrict__ Wk,
    const float* __restrict__ bk, float* __restrict__ uws)
{
    const int tid = threadIdx.x;
    const int b   = blockIdx.x;
    const float* Xb = x_seq + (size_t)b * (SS * DD);

    __shared__ __attribute__((aligned(16))) union {
        double T[8][512];       // t, head-major (32 KB)
        double P[4][8][128];    // qk quarter-partials (32 KB)
    } sh;
    __shared__ __attribute__((aligned(16))) union {
        double qd[512];         // q[b] (4 KB)
        float  attn[8][128];    // logits/exp (4 KB)
    } sh2;
    __shared__ double qbks[8];
    __shared__ float  lsums[8];

    // ---- load q[b] (f64, coalesced) ----
    sh2.qd[tid]       = qws[(size_t)b * DD + tid];
    sh2.qd[tid + 256] = qws[(size_t)b * DD + tid + 256];
    __syncthreads();

    // ---- qbk[h] = q_h . bk_h (wave 0, 8 lanes per head) ----
    if (tid < 64) {
        const int h = tid >> 3, part = tid & 7;
        double s = 0.0;
        #pragma unroll
        for (int ii = 0; ii < 8; ++ii) {
            int d = part * 8 + ii;
            s = fma(sh2.qd[h * DHH + d], (double)bk[h * DHH + d], s);
        }
        s += __shfl_xor(s, 1);
        s += __shfl_xor(s, 2);
        s += __shfl_xor(s, 4);
        if (part == 0) qbks[h] = s;
    }

    // ---- t: lanes = k (coalesced f4 Wk loads); d split across thread halves ----
    {
        const int kg = tid & 127, dh = tid >> 7;
        const int k4 = kg * 4;
        for (int hg = 0; hg < 2; ++hg) {
            double tacc[4][4];
            #pragma unroll
            for (int h4 = 0; h4 < 4; ++h4) {
                const int h = hg * 4 + h4;
                const float* wp = Wk + ((size_t)(h * DHH + dh * 32)) * DD + k4;
                double t0 = 0, t1 = 0, t2 = 0, t3 = 0;
                for (int d = 0; d < 32; ++d) {
                    f4 wv = *(const f4*)(wp + (size_t)d * DD);
                    double qv = sh2.qd[h * DHH + dh * 32 + d];
                    t0 = fma((double)wv[0], qv, t0);
                    t1 = fma((double)wv[1], qv, t1);
                    t2 = fma((double)wv[2], qv, t2);
                    t3 = fma((double)wv[3], qv, t3);
                }
                tacc[h4][0] = t0; tacc[h4][1] = t1; tacc[h4][2] = t2; tacc[h4][3] = t3;
            }
            if (dh == 1) {
                #pragma unroll
                for (int h4 = 0; h4 < 4; ++h4)
                    #pragma unroll
                    for (int e = 0; e < 4; ++e)
                        sh.T[hg * 4 + h4][k4 + e] = tacc[h4][e];
            }
            __syncthreads();
            if (dh == 0) {
                #pragma unroll
                for (int h4 = 0; h4 < 4; ++h4)
                    #pragma unroll
                    for (int e = 0; e < 4; ++e)
                        sh.T[hg * 4 + h4][k4 + e] += tacc[h4][e];
            }
            __syncthreads();
        }
    }

    // ---- qk partials: wave = k-quarter, lane = rows s=l, l+64 ----
    const int qw = tid >> 6, l = tid & 63;
    double acc0[8], acc1[8];
    #pragma unroll
    for (int h = 0; h < 8; ++h) { acc0[h] = 0.0; acc1[h] = 0.0; }
    {
        const int k0 = qw * 128;
        const float* xa = Xb + (size_t)l * DD + k0;
        const float* xc = xa + (size_t)64 * DD;
        for (int j = 0; j < 128; j += 4) {
            f4 xva = *(const f4*)(xa + j);
            f4 xvc = *(const f4*)(xc + j);
            #pragma unroll
            for (int h = 0; h < 8; ++h) {
                d2 t01 = *(const d2*)&sh.T[h][k0 + j];
                d2 t23 = *(const d2*)&sh.T[h][k0 + j + 2];
                acc0[h] = fma((double)xva[0], t01[0], acc0[h]);
                acc1[h] = fma((double)xvc[0], t01[0], acc1[h]);
                acc0[h] = fma((double)xva[1], t01[1], acc0[h]);
                acc1[h] = fma((double)xvc[1], t01[1], acc1[h]);
                acc0[h] = fma((double)xva[2], t23[0], acc0[h]);
                acc1[h] = fma((double)xvc[2], t23[0], acc1[h]);
                acc0[h] = fma((double)xva[3], t23[1], acc0[h]);
                acc1[h] = fma((double)xvc[3], t23[1], acc1[h]);
            }
        }
    }
    __syncthreads();                 // T fully read; P aliases it
    #pragma unroll
    for (int h = 0; h < 8; ++h) {
        sh.P[qw][h][l]      = acc0[h];
        sh.P[qw][h][l + 64] = acc1[h];
    }
    __syncthreads();

    // ---- reduce quarters, floor(/8), mask (coalesced mask read) ----
    #pragma unroll
    for (int p = 0; p < 4; ++p) {
        int slot = tid + 256 * p;              // h = slot>>7, s = slot&127
        int h = slot >> 7, s2 = slot & 127;
        double tot = sh.P[0][h][s2] + sh.P[1][h][s2]
                   + sh.P[2][h][s2] + sh.P[3][h][s2] + qbks[h];
        double sc = floor(tot * 0.125);
        if (mask[(size_t)b * (NHH * SS) + slot] == 0) sc = -1e9;
        sh2.attn[h][s2] = (float)sc;
    }
    __syncthreads();

    // ---- softmax per head (32-lane groups), unnormalized ----
    {
        const int h = tid >> 5, i = tid & 31;
        float v[4], mx = -3e38f;
        #pragma unroll
        for (int jj = 0; jj < 4; ++jj) { v[jj] = sh2.attn[h][i + 32 * jj]; mx = fmaxf(mx, v[jj]); }
        #pragma unroll
        for (int off = 1; off < 32; off <<= 1) mx = fmaxf(mx, __shfl_xor(mx, off, 32));
        float sum = 0.f;
        #pragma unroll
        for (int jj = 0; jj < 4; ++jj) { v[jj] = expf(v[jj] - mx); sum += v[jj]; }
        #pragma unroll
        for (int off = 1; off < 32; off <<= 1) sum += __shfl_xor(sum, off, 32);
        #pragma unroll
        for (int jj = 0; jj < 4; ++jj) sh2.attn[h][i + 32 * jj] = v[jj];
        if (i == 0) lsums[h] = sum;
    }
    __syncthreads();

    // ---- u'[h,k] = (attn_h @ X)/lsum_h  (coalesced X, k = tid, tid+256) ----
    {
        float a1[8], a2[8];
        #pragma unroll
        for (int h = 0; h < 8; ++h) { a1[h] = 0.f; a2[h] = 0.f; }
        for (int s2 = 0; s2 < SS; s2 += 4) {
            f4 av[8];
            #pragma unroll
            for (int h = 0; h < 8; ++h) av[h] = *(const f4*)&sh2.attn[h][s2];
            #pragma unroll
            for (int e = 0; e < 4; ++e) {
                float x1 = Xb[(size_t)(s2 + e) * DD + tid];
                float x2 = Xb[(size_t)(s2 + e) * DD + tid + 256];
                #pragma unroll
                for (int h = 0; h < 8; ++h) {
                    a1[h] = fmaf(av[h][e], x1, a1[h]);
                    a2[h] = fmaf(av[h][e], x2, a2[h]);
                }
            }
        }
        #pragma unroll
        for (int h = 0; h < 8; ++h) {
            float inv = 1.0f / lsums[h];
            uws[((size_t)b * NHH + h) * DD + tid]       = a1[h] * inv;
            uws[((size_t)b * NHH + h) * DD + tid + 256] = a2[h] * inv;
        }
    }
}

// ================= K3: z[b, h*64+j] = u'[b,h,:] . Wv[o,:] + bv[o]  (f32) ======
// 256 blocks: 32 b-tiles (32) x 8 o-tiles (64; o-tile == head). Wv LDS-staged.
__global__ __launch_bounds__(256) void zout_kernel(
    const float* __restrict__ uws, const float* __restrict__ Wv,
    const float* __restrict__ bv, float* __restrict__ out)
{
    const int tid = threadIdx.x;
    const int bt  = blockIdx.x & 31;
    const int ot  = blockIdx.x >> 5;          // == head h
    const int r   = tid >> 4, c = tid & 15;

    __shared__ __attribute__((aligned(16))) float Us[32][68];
    __shared__ __attribute__((aligned(16))) float Ws[64][68];

    float acc[2][4];
    #pragma unroll
    for (int i = 0; i < 2; ++i)
        #pragma unroll
        for (int j = 0; j < 4; ++j) acc[i][j] = 0.f;

    for (int kc = 0; kc < 8; ++kc) {
        __syncthreads();
        #pragma unroll
        for (int p = 0; p < 2; ++p) {
            int s = tid + 256 * p, rr = s >> 4, cc = (s & 15) * 4;
            *(f4*)&Us[rr][cc] =
                *(const f4*)(uws + ((size_t)(bt * 32 + rr) * NHH + ot) * DD + kc * 64 + cc);
        }
        #pragma unroll
        for (int p = 0; p < 4; ++p) {
            int s = tid + 256 * p, rr = s >> 4, cc = (s & 15) * 4;
            *(f4*)&Ws[rr][cc] = *(const f4*)(Wv + (size_t)(ot * 64 + rr) * DD + kc * 64 + cc);
        }
        __syncthreads();
        #pragma unroll 4
        for (int kk = 0; kk < 64; ++kk) {
            float a0 = Us[r][kk];
            float a1 = Us[r + 16][kk];
            #pragma unroll
            for (int j = 0; j < 4; ++j) {
                float bb = Ws[c + 16 * j][kk];
                acc[0][j] = fmaf(a0, bb, acc[0][j]);
                acc[1][j] = fmaf(a1, bb, acc[1][j]);
            }
        }
    }
    #pragma unroll
    for (int i = 0; i < 2; ++i)
        #pragma unroll
        for (int j = 0; j < 4; ++j) {
            int o = ot * 64 + c + 16 * j;
            out[(size_t)(bt * 32 + r + 16 * i) * DD + o] = acc[i][j] + bv[o];
        }
}

extern "C" void kernel_launch(void* const* d_in, const int* in_sizes, int n_in,
                              void* d_out, int out_size, void* d_ws, size_t ws_size,
                              hipStream_t stream) {
    const float* x_non = (const float*)d_in[0];
    const float* x_seq = (const float*)d_in[1];
    const int*   mask  = (const int*)d_in[2];
    const float* Wq    = (const float*)d_in[3];
    const float* bq    = (const float*)d_in[4];
    const float* Wk    = (const float*)d_in[5];
    const float* bk    = (const float*)d_in[6];
    const float* Wv    = (const float*)d_in[7];
    const float* bv    = (const float*)d_in[8];
    float*       out   = (float*)d_out;

    double* qws = (double*)d_ws;                                     // 4 MB
    float*  uws = (float*)((char*)d_ws + (size_t)1024 * DD * 8);     // 16 MB

    qproj_kernel<<<256, 256, 0, stream>>>(x_non, Wq, bq, qws);
    core_kernel<<<1024, 256, 0, stream>>>(qws, x_seq, mask, Wk, bk, uws);
    zout_kernel<<<256, 256, 0, stream>>>(uws, Wv, bv, out);
}